// Round 8
// baseline (96.004 us; speedup 1.0000x reference)
//
#include <hip/hip_runtime.h>
#include <hip/hip_bf16.h>

// Flash attention fwd, swapped-QK^T 32x32x16 MFMA, in-register softmax,
// INTRA-BLOCK KV SPLIT for TLP. BH=32, S=2048, D=64, B=2 key-padding masks.
// Block = 512 thr (8 waves): waves 0-3 = keys 0..1023, waves 4-7 = keys
// 1024..2047, SAME 128 q rows; merge (O,m,l) via LDS at the end.
// __launch_bounds__(512, 2): hipcc's 2nd arg acts as min BLOCKS/CU here —
// (512,4) produced a 64-VGPR cap (32 waves/CU step) and force-spilled the
// ~110-reg live set (r6: 135us, 55MB spill writes; r7: 83us, 12MB).
// (512,2) -> 128-VGPR cap, 2 blocks/CU x 8 waves = 4 waves/SIMD, no spill.
// Staging loads issued AFTER softmax (s0/s1 dead), written after PV;
// sched_barrier(0) pins the issue point against pre-RA hoisting.
// S^T = mfma(K, Q): lane owns q = lane&31; softmax in-lane + permlane32_swap.
// P in registers (cvt_pk bf16 + permlane32_swap) -> PV: O^T = mfma(V^T, P^T).
// LDS: fragment-linear chunks (conflict-free frag reads), 2x dbuf/half = 64KB.
// T5 setprio, T13 defer-rescale, exp2 domain.

#define SQ 2048
#define DD 64
#define NT2 16   // tiles per half: 1024 / 64

typedef __attribute__((ext_vector_type(8)))  short bf16x8;
typedef __attribute__((ext_vector_type(16))) float f32x16;
typedef __attribute__((ext_vector_type(2)))  unsigned uint2v;

#define LOG2E  1.4426950408889634f
#define QSCALE (0.125f * LOG2E)
#define MASKV  (-4294967295.0f * LOG2E)   // MASK_NUM in log2 domain
#define THRL   (8.0f * LOG2E)             // defer-rescale threshold

__device__ __forceinline__ int cvt_pk(float lo, float hi) {
    int r;
    asm("v_cvt_pk_bf16_f32 %0, %1, %2" : "=v"(r) : "v"(lo), "v"(hi));
    return r;
}
// fragment-linear chunk addressing: chunk c (0..7), element e (0..63)
__device__ __forceinline__ int koff(int c, int e) {
    return c * 1024 + ((e ^ (((c & 3) << 1) | (e >> 5))) << 4);
}
// orientation-independent cross-half combines (swap(x,x) = both row-bcasts)
__device__ __forceinline__ float xmax(float x) {
#if __has_builtin(__builtin_amdgcn_permlane32_swap)
    union { float f; unsigned u; } a; a.f = x;
    uint2v r = __builtin_amdgcn_permlane32_swap(a.u, a.u, false, false);
    union { unsigned u; float f; } p0, p1; p0.u = r[0]; p1.u = r[1];
    return fmaxf(p0.f, p1.f);
#else
    return fmaxf(x, __shfl_xor(x, 32));
#endif
}
__device__ __forceinline__ float xsum(float x) {
#if __has_builtin(__builtin_amdgcn_permlane32_swap)
    union { float f; unsigned u; } a; a.f = x;
    uint2v r = __builtin_amdgcn_permlane32_swap(a.u, a.u, false, false);
    union { unsigned u; float f; } p0, p1; p0.u = r[0]; p1.u = r[1];
    return p0.f + p1.f;
#else
    return x + __shfl_xor(x, 32);
#endif
}
// PV B-operand words: a = pk[2kp] (keys 16kp+4hi..+3), b = pk[2kp+1] (+8).
__device__ __forceinline__ void plswap2(unsigned a, unsigned b,
                                        unsigned& lo01, unsigned& hi23, int hi) {
#if __has_builtin(__builtin_amdgcn_permlane32_swap)
    uint2v r = __builtin_amdgcn_permlane32_swap(a, b, false, false);
    lo01 = r[0]; hi23 = r[1];
#else
    unsigned pa = (unsigned)__shfl_xor((int)a, 32);
    unsigned pb = (unsigned)__shfl_xor((int)b, 32);
    lo01 = hi ? pb : a;
    hi23 = hi ? b : pa;
#endif
}

__global__ __launch_bounds__(512, 2) void attn_fwd(
    const float* __restrict__ q, const float* __restrict__ k,
    const float* __restrict__ v, const int* __restrict__ masks,
    float* __restrict__ out)
{
    // per half: buf0 {K 8K, V 8K}, buf1 {K 8K, V 8K} = 32KB; two halves = 64KB.
    __shared__ alignas(16) char smem[65536];

    const int x    = blockIdx.x;
    const int orig = (x & 7) * 64 + (x >> 3);  // bijective XCD swizzle (512=8*64)
    const int h    = orig >> 4;                // 4 heads/XCD -> K/V L2 reuse
    const int qb   = orig & 15;
    const int tid  = threadIdx.x;
    const int w8   = tid >> 6;
    const int half = w8 >> 2;                  // 0: keys 0..1023, 1: 1024..2047
    const int w    = w8 & 3;                   // q sub-block within 128 rows
    const int lane = tid & 63;
    const int l31  = lane & 31;
    const int hi   = lane >> 5;
    const int lt   = tid & 255;                // staging index within half
    const int kb0  = half << 10;

    const float* __restrict__ qh = q + (size_t)h * SQ * DD;
    const float* __restrict__ kh = k + (size_t)h * SQ * DD;
    const float* __restrict__ vh = v + (size_t)h * SQ * DD;
    const int*   __restrict__ mrow = masks + (h & 1) * SQ;   // bh % 2

    // ---- Q fragments (B-operand: col=q=l31, k=d chunk), log2e*0.125 scale ----
    const int qrow = qb * 128 + w * 32 + l31;
    bf16x8 qf[4];
#pragma unroll
    for (int dc = 0; dc < 4; ++dc) {
        const float* p = qh + (size_t)qrow * DD + dc * 16 + hi * 8;
        float4 a = *(const float4*)p;
        float4 b = *(const float4*)(p + 4);
        union { int i[4]; bf16x8 v; } f;
        f.i[0] = cvt_pk(a.x * QSCALE, a.y * QSCALE);
        f.i[1] = cvt_pk(a.z * QSCALE, a.w * QSCALE);
        f.i[2] = cvt_pk(b.x * QSCALE, b.y * QSCALE);
        f.i[3] = cvt_pk(b.z * QSCALE, b.w * QSCALE);
        qf[dc] = f.v;
    }

    f32x16 o[2];
#pragma unroll
    for (int dt = 0; dt < 2; ++dt)
#pragma unroll
      for (int i = 0; i < 16; ++i) o[dt][i] = 0.f;
    float m = -3.0e38f, l = 0.f;

    // staging slots (256 thr/half): K rows {rK,rK+32} x 8d; V pair {2aV,2aV+1} x 8d
    const int rK = lt >> 3, cK = lt & 7;
    const int aV = lt & 31, dV = (lt >> 5) * 8;
    const int eK = ((cK & 1) << 5) | rK;
    const int kA_off = koff(cK >> 1,       eK);
    const int kB_off = koff(4 + (cK >> 1), eK);
    char* const Hb = smem + (half << 15);      // this half's 32KB

    float4 kA0, kA1, kB0, kB1, vA0, vA1, vB0, vB1;
#define LOADKV(kt)                                                        \
    {   const float* kpA = kh + (size_t)((kt) + rK) * DD + 8 * cK;       \
        const float* kpB = kpA + 32 * DD;                                 \
        const float* vpA = vh + (size_t)((kt) + 2 * aV) * DD + dV;       \
        const float* vpB = vpA + DD;                                      \
        kA0 = *(const float4*)kpA; kA1 = *(const float4*)(kpA + 4);      \
        kB0 = *(const float4*)kpB; kB1 = *(const float4*)(kpB + 4);      \
        vA0 = *(const float4*)vpA; vA1 = *(const float4*)(vpA + 4);      \
        vB0 = *(const float4*)vpB; vB1 = *(const float4*)(vpB + 4);      }

#define WRITEKV(Kp, Vp)                                                   \
    {   union { int i[4]; bf16x8 b; } kw;                                 \
        kw.i[0] = cvt_pk(kA0.x, kA0.y); kw.i[1] = cvt_pk(kA0.z, kA0.w);  \
        kw.i[2] = cvt_pk(kA1.x, kA1.y); kw.i[3] = cvt_pk(kA1.z, kA1.w);  \
        *(bf16x8*)((Kp) + kA_off) = kw.b;                                 \
        kw.i[0] = cvt_pk(kB0.x, kB0.y); kw.i[1] = cvt_pk(kB0.z, kB0.w);  \
        kw.i[2] = cvt_pk(kB1.x, kB1.y); kw.i[3] = cvt_pk(kB1.z, kB1.w);  \
        *(bf16x8*)((Kp) + kB_off) = kw.b;                                 \
        float va[8] = {vA0.x, vA0.y, vA0.z, vA0.w, vA1.x, vA1.y, vA1.z, vA1.w}; \
        float vb[8] = {vB0.x, vB0.y, vB0.z, vB0.w, vB1.x, vB1.y, vB1.z, vB1.w}; \
        _Pragma("unroll")                                                 \
        for (int j = 0; j < 8; ++j) {                                     \
            const int r_ = dV + j;                                        \
            const int cv_ = ((aV >> 3) << 1) | (r_ >> 5);                 \
            const int ev_ = (((aV >> 2) & 1) << 5) | (r_ & 31);           \
            *(unsigned*)((Vp) + koff(cv_, ev_) + 4 * (aV & 3))            \
                = (unsigned)cvt_pk(va[j], vb[j]);                         \
        }                                                                 }

    LOADKV(kb0)
    WRITEKV(Hb, Hb + 8192)
    __syncthreads();

    int boff = 0;
    for (int it = 0; it < NT2; ++it) {
        const int kt = kb0 + it * 64;
        const bool more = (it + 1 < NT2);
        char* Kb = Hb + boff;
        char* Vb = Kb + 8192;

        // ---- QK^T (swapped): s[kb] = S^T[32kb+key][q]; C-init = mask addend ----
        const int* mk = mrow + kt + 4 * hi;
        f32x16 s0, s1;
#pragma unroll
        for (int g = 0; g < 4; ++g) {
            int4 a = *(const int4*)(mk + 8 * g);
            int4 b = *(const int4*)(mk + 32 + 8 * g);
            s0[4*g+0] = a.x ? MASKV : 0.f; s0[4*g+1] = a.y ? MASKV : 0.f;
            s0[4*g+2] = a.z ? MASKV : 0.f; s0[4*g+3] = a.w ? MASKV : 0.f;
            s1[4*g+0] = b.x ? MASKV : 0.f; s1[4*g+1] = b.y ? MASKV : 0.f;
            s1[4*g+2] = b.z ? MASKV : 0.f; s1[4*g+3] = b.w ? MASKV : 0.f;
        }
        __builtin_amdgcn_s_setprio(1);
#pragma unroll
        for (int dc = 0; dc < 4; ++dc) {
            bf16x8 k0 = *(const bf16x8*)(Kb + koff(dc,     lane));
            bf16x8 k1 = *(const bf16x8*)(Kb + koff(4 + dc, lane));
            s0 = __builtin_amdgcn_mfma_f32_32x32x16_bf16(k0, qf[dc], s0, 0, 0, 0);
            s1 = __builtin_amdgcn_mfma_f32_32x32x16_bf16(k1, qf[dc], s1, 0, 0, 0);
        }
        __builtin_amdgcn_s_setprio(0);

        // ---- in-lane max tree + cross-half combine ----
        float t[16];
#pragma unroll
        for (int i = 0; i < 16; ++i) t[i] = fmaxf(s0[i], s1[i]);
#pragma unroll
        for (int stp = 8; stp >= 1; stp >>= 1)
#pragma unroll
            for (int i = 0; i < stp; ++i) t[i] = fmaxf(t[i], t[i + stp]);
        float pmax = xmax(t[0]);

        float mn = m;
        if (!__all(pmax <= m + THRL)) {       // T13 defer-rescale
            mn = fmaxf(m, pmax);
            float al = __builtin_amdgcn_exp2f(m - mn);
            l *= al;
#pragma unroll
            for (int dt = 0; dt < 2; ++dt)
#pragma unroll
              for (int i = 0; i < 16; ++i) o[dt][i] *= al;
            m = mn;
        }

        // P in-place over S (register economy)
#pragma unroll
        for (int i = 0; i < 16; ++i) {
            s0[i] = __builtin_amdgcn_exp2f(s0[i] - mn);
            s1[i] = __builtin_amdgcn_exp2f(s1[i] - mn);
        }
        float u[16];
#pragma unroll
        for (int i = 0; i < 16; ++i) u[i] = s0[i] + s1[i];
#pragma unroll
        for (int stp = 8; stp >= 1; stp >>= 1)
#pragma unroll
            for (int i = 0; i < stp; ++i) u[i] += u[i + stp];
        l += xsum(u[0]);

        // ---- pack P -> bf16 pairs (keys (8g+4hi)..+3 per group g); s dies here ----
        unsigned pk[2][4][2];
#pragma unroll
        for (int g = 0; g < 4; ++g) {
            pk[0][g][0] = (unsigned)cvt_pk(s0[4*g+0], s0[4*g+1]);
            pk[0][g][1] = (unsigned)cvt_pk(s0[4*g+2], s0[4*g+3]);
            pk[1][g][0] = (unsigned)cvt_pk(s1[4*g+0], s1[4*g+1]);
            pk[1][g][1] = (unsigned)cvt_pk(s1[4*g+2], s1[4*g+3]);
        }

        // ---- stage next tile: issue NOW (s dead), write after PV ----
        __builtin_amdgcn_sched_barrier(0);   // don't hoist loads above softmax
        if (more) LOADKV(kt + 64)

        // ---- PV: O^T += V^T . P^T (P exchanged via permlane32_swap) ----
        __builtin_amdgcn_s_setprio(1);
#pragma unroll
        for (int kc = 0; kc < 4; ++kc) {
            const int kb = kc >> 1, kp = kc & 1;
            union { unsigned u[4]; bf16x8 b; } pu;
            unsigned lo0, hi0, lo1, hi1;
            plswap2(pk[kb][2*kp][0], pk[kb][2*kp+1][0], lo0, hi0, hi);
            plswap2(pk[kb][2*kp][1], pk[kb][2*kp+1][1], lo1, hi1, hi);
            pu.u[0] = lo0; pu.u[1] = lo1; pu.u[2] = hi0; pu.u[3] = hi1;
#pragma unroll
            for (int dt = 0; dt < 2; ++dt) {
                bf16x8 vf = *(const bf16x8*)(Vb + koff(kc * 2 + dt, lane));
                o[dt] = __builtin_amdgcn_mfma_f32_32x32x16_bf16(vf, pu.b, o[dt], 0, 0, 0);
            }
        }
        __builtin_amdgcn_s_setprio(0);

        if (more) {                        // write next tile into other buffer
            char* Kn = Hb + (boff ^ 16384);
            WRITEKV(Kn, Kn + 8192)
        }

        __syncthreads();          // cur reads done + next buffer visible
        boff ^= 16384;
    }

    // ---- merge halves: pair (w, w+4) shares q rows; half1 -> LDS, half0 merges ----
    float* pr = (float*)(smem + w * 8704);   // [reg 0..31][lane] + m[64] + l[64]
    if (half) {
#pragma unroll
        for (int dt = 0; dt < 2; ++dt)
#pragma unroll
          for (int i = 0; i < 16; ++i)
            pr[(dt * 16 + i) * 64 + lane] = o[dt][i];
        pr[2048 + lane] = m;
        pr[2112 + lane] = l;
    }
    __syncthreads();
    if (!half) {
        const float m1 = pr[2048 + lane];
        const float l1 = pr[2112 + lane];
        const float M  = fmaxf(m, m1);
        const float a0 = __builtin_amdgcn_exp2f(m - M);
        const float a1 = __builtin_amdgcn_exp2f(m1 - M);
        const float invl = 1.0f / (a0 * l + a1 * l1);
        float* op = out + (size_t)h * SQ * DD + (size_t)qrow * DD;
#pragma unroll
        for (int dt = 0; dt < 2; ++dt)
#pragma unroll
          for (int g = 0; g < 4; ++g) {
            float4 r;
            r.x = (a0 * o[dt][4*g+0] + a1 * pr[(dt*16 + 4*g+0) * 64 + lane]) * invl;
            r.y = (a0 * o[dt][4*g+1] + a1 * pr[(dt*16 + 4*g+1) * 64 + lane]) * invl;
            r.z = (a0 * o[dt][4*g+2] + a1 * pr[(dt*16 + 4*g+2) * 64 + lane]) * invl;
            r.w = (a0 * o[dt][4*g+3] + a1 * pr[(dt*16 + 4*g+3) * 64 + lane]) * invl;
            *(float4*)(op + 32 * dt + 8 * g + 4 * hi) = r;
          }
    }
}

extern "C" void kernel_launch(void* const* d_in, const int* in_sizes, int n_in,
                              void* d_out, int out_size, void* d_ws, size_t ws_size,
                              hipStream_t stream) {
    const float* q = (const float*)d_in[0];
    const float* k = (const float*)d_in[1];
    const float* v = (const float*)d_in[2];
    const int* masks = (const int*)d_in[3];
    float* out = (float*)d_out;
    attn_fwd<<<dim3(512), dim3(512), 0, stream>>>(q, k, v, masks, out);
}

// Round 9
// 64.224 us; speedup vs baseline: 1.4948x; 1.4948x over previous
//
#include <hip/hip_runtime.h>
#include <hip/hip_bf16.h>

// Flash attention fwd, swapped-QK^T 32x32x16 MFMA, in-register softmax.
// BH=32, S=2048, D=64, B=2 key-padding masks.
// Block = 256 thr (4 waves), wave = 32 q rows; grid 512 (2 blocks/CU).
// r6-r8 KV-split arc REVERTED: total waves are problem-capped at 2/SIMD and
// doubling TLP via split ran slower (merge + 8-wave barriers + 2x staging
// streams). This is r5 (62.6us) plus:
//  - LOADKV pinned at tile top via sched_barrier(0) AFTER it: loads stay
//    issued across QK+softmax+PV (~800+cyc = HBM-miss cover). r5 let the
//    scheduler sink them (VGPR 76 = short live range). (256,2) -> VGPR cap
//    256 (8 waves/CU), so the ~110-reg live set cannot spill (r6 trap was
//    (512,4)'s 64-cap).
//  - WRITEKV post-PV (max load->use gap).
//  - max3-shaped max tree (v_max3_f32 fusion).
// S^T = mfma(K, Q): lane owns q = lane&31; softmax in-lane + permlane32_swap.
// P in registers (cvt_pk bf16 + permlane32_swap) -> PV: O^T = mfma(V^T, P^T).
// LDS: fragment-linear chunks (conflict-free frag reads), dbuf + mask = 40KB.
// T5 setprio, T13 defer-rescale, exp2 domain.

#define SQ 2048
#define DD 64
#define NT 32   // 2048 / 64 KV tiles

typedef __attribute__((ext_vector_type(8)))  short bf16x8;
typedef __attribute__((ext_vector_type(16))) float f32x16;
typedef __attribute__((ext_vector_type(2)))  unsigned uint2v;

#define LOG2E  1.4426950408889634f
#define QSCALE (0.125f * LOG2E)
#define MASKV  (-4294967295.0f * LOG2E)   // MASK_NUM in log2 domain
#define THRL   (8.0f * LOG2E)             // defer-rescale threshold

__device__ __forceinline__ int cvt_pk(float lo, float hi) {
    int r;
    asm("v_cvt_pk_bf16_f32 %0, %1, %2" : "=v"(r) : "v"(lo), "v"(hi));
    return r;
}
__device__ __forceinline__ float max3f(float a, float b, float c) {
    return fmaxf(fmaxf(a, b), c);        // clang fuses to v_max3_f32
}
// fragment-linear chunk addressing: chunk c (0..7), element e (0..63)
__device__ __forceinline__ int koff(int c, int e) {
    return c * 1024 + ((e ^ (((c & 3) << 1) | (e >> 5))) << 4);
}
// orientation-independent cross-half combines (swap(x,x) = both row-bcasts)
__device__ __forceinline__ float xmax(float x) {
#if __has_builtin(__builtin_amdgcn_permlane32_swap)
    union { float f; unsigned u; } a; a.f = x;
    uint2v r = __builtin_amdgcn_permlane32_swap(a.u, a.u, false, false);
    union { unsigned u; float f; } p0, p1; p0.u = r[0]; p1.u = r[1];
    return fmaxf(p0.f, p1.f);
#else
    return fmaxf(x, __shfl_xor(x, 32));
#endif
}
__device__ __forceinline__ float xsum(float x) {
#if __has_builtin(__builtin_amdgcn_permlane32_swap)
    union { float f; unsigned u; } a; a.f = x;
    uint2v r = __builtin_amdgcn_permlane32_swap(a.u, a.u, false, false);
    union { unsigned u; float f; } p0, p1; p0.u = r[0]; p1.u = r[1];
    return p0.f + p1.f;
#else
    return x + __shfl_xor(x, 32);
#endif
}
// PV B-operand words: a = pk[2kp] (keys 16kp+4hi..+3), b = pk[2kp+1] (+8).
__device__ __forceinline__ void plswap2(unsigned a, unsigned b,
                                        unsigned& lo01, unsigned& hi23, int hi) {
#if __has_builtin(__builtin_amdgcn_permlane32_swap)
    uint2v r = __builtin_amdgcn_permlane32_swap(a, b, false, false);
    lo01 = r[0]; hi23 = r[1];
#else
    unsigned pa = (unsigned)__shfl_xor((int)a, 32);
    unsigned pb = (unsigned)__shfl_xor((int)b, 32);
    lo01 = hi ? pb : a;
    hi23 = hi ? b : pa;
#endif
}

__global__ __launch_bounds__(256, 2) void attn_fwd(
    const float* __restrict__ q, const float* __restrict__ k,
    const float* __restrict__ v, const int* __restrict__ masks,
    float* __restrict__ out)
{
    // buf0: K@0 V@8192 | buf1: K@16384 V@24576 | mask @32768 (8KB)
    __shared__ alignas(16) char smem[40960];
    float* Mf = (float*)(smem + 32768);

    const int x    = blockIdx.x;
    const int orig = (x & 7) * 64 + (x >> 3);  // bijective XCD swizzle (512=8*64)
    const int h    = orig >> 4;                // 4 heads/XCD -> K/V L2 reuse
    const int qb   = orig & 15;
    const int tid  = threadIdx.x;
    const int w    = tid >> 6;
    const int lane = tid & 63;
    const int l31  = lane & 31;
    const int hi   = lane >> 5;

    const float* __restrict__ qh = q + (size_t)h * SQ * DD;
    const float* __restrict__ kh = k + (size_t)h * SQ * DD;
    const float* __restrict__ vh = v + (size_t)h * SQ * DD;
    const int*   __restrict__ mrow = masks + (h & 1) * SQ;   // bh % 2

    // ---- stage mask addend table once (2048 floats) ----
    {
        int4 a = *(const int4*)(mrow + tid * 8);
        int4 b = *(const int4*)(mrow + tid * 8 + 4);
        float4 fa = { a.x ? MASKV : 0.f, a.y ? MASKV : 0.f,
                      a.z ? MASKV : 0.f, a.w ? MASKV : 0.f };
        float4 fb = { b.x ? MASKV : 0.f, b.y ? MASKV : 0.f,
                      b.z ? MASKV : 0.f, b.w ? MASKV : 0.f };
        *(float4*)(Mf + tid * 8)     = fa;
        *(float4*)(Mf + tid * 8 + 4) = fb;
    }

    // ---- Q fragments (B-operand: col=q=l31, k=d chunk), log2e*0.125 scale ----
    const int qrow = qb * 128 + w * 32 + l31;
    bf16x8 qf[4];
#pragma unroll
    for (int dc = 0; dc < 4; ++dc) {
        const float* p = qh + (size_t)qrow * DD + dc * 16 + hi * 8;
        float4 a = *(const float4*)p;
        float4 b = *(const float4*)(p + 4);
        union { int i[4]; bf16x8 v; } f;
        f.i[0] = cvt_pk(a.x * QSCALE, a.y * QSCALE);
        f.i[1] = cvt_pk(a.z * QSCALE, a.w * QSCALE);
        f.i[2] = cvt_pk(b.x * QSCALE, b.y * QSCALE);
        f.i[3] = cvt_pk(b.z * QSCALE, b.w * QSCALE);
        qf[dc] = f.v;
    }

    f32x16 o[2];
#pragma unroll
    for (int dt = 0; dt < 2; ++dt)
#pragma unroll
      for (int i = 0; i < 16; ++i) o[dt][i] = 0.f;
    float m = -3.0e38f, l = 0.f;

    // staging slots (256 thr): K rows {rK,rK+32} x 8d; V key-pair {2aV,2aV+1} x 8d
    const int rK = tid >> 3, cK = tid & 7;
    const int aV = tid & 31, dV = (tid >> 5) * 8;
    const int eK = ((cK & 1) << 5) | rK;
    const int kA_off = koff(cK >> 1,       eK);
    const int kB_off = koff(4 + (cK >> 1), eK);

    float4 kA0, kA1, kB0, kB1, vA0, vA1, vB0, vB1;
#define LOADKV(kt)                                                        \
    {   const float* kpA = kh + (size_t)((kt) + rK) * DD + 8 * cK;       \
        const float* kpB = kpA + 32 * DD;                                 \
        const float* vpA = vh + (size_t)((kt) + 2 * aV) * DD + dV;       \
        const float* vpB = vpA + DD;                                      \
        kA0 = *(const float4*)kpA; kA1 = *(const float4*)(kpA + 4);      \
        kB0 = *(const float4*)kpB; kB1 = *(const float4*)(kpB + 4);      \
        vA0 = *(const float4*)vpA; vA1 = *(const float4*)(vpA + 4);      \
        vB0 = *(const float4*)vpB; vB1 = *(const float4*)(vpB + 4);      }

#define WRITEKV(Kp, Vp)                                                   \
    {   union { int i[4]; bf16x8 b; } kw;                                 \
        kw.i[0] = cvt_pk(kA0.x, kA0.y); kw.i[1] = cvt_pk(kA0.z, kA0.w);  \
        kw.i[2] = cvt_pk(kA1.x, kA1.y); kw.i[3] = cvt_pk(kA1.z, kA1.w);  \
        *(bf16x8*)((Kp) + kA_off) = kw.b;                                 \
        kw.i[0] = cvt_pk(kB0.x, kB0.y); kw.i[1] = cvt_pk(kB0.z, kB0.w);  \
        kw.i[2] = cvt_pk(kB1.x, kB1.y); kw.i[3] = cvt_pk(kB1.z, kB1.w);  \
        *(bf16x8*)((Kp) + kB_off) = kw.b;                                 \
        float va[8] = {vA0.x, vA0.y, vA0.z, vA0.w, vA1.x, vA1.y, vA1.z, vA1.w}; \
        float vb[8] = {vB0.x, vB0.y, vB0.z, vB0.w, vB1.x, vB1.y, vB1.z, vB1.w}; \
        _Pragma("unroll")                                                 \
        for (int j = 0; j < 8; ++j) {                                     \
            const int r_ = dV + j;                                        \
            const int cv_ = ((aV >> 3) << 1) | (r_ >> 5);                 \
            const int ev_ = (((aV >> 2) & 1) << 5) | (r_ & 31);           \
            *(unsigned*)((Vp) + koff(cv_, ev_) + 4 * (aV & 3))            \
                = (unsigned)cvt_pk(va[j], vb[j]);                         \
        }                                                                 }

    LOADKV(0)
    WRITEKV(smem, smem + 8192)
    __syncthreads();

    int boff = 0;
    for (int it = 0; it < NT; ++it) {
        const int kt = it * 64;
        const bool more = (it + 1 < NT);

        // ---- T14 issue-early: loads for t+1 pinned HERE, consumed post-PV ----
        if (more) LOADKV(kt + 64)
        __builtin_amdgcn_sched_barrier(0);   // pin: no sinking toward WRITEKV

        char* Kb = smem + boff;
        char* Vb = Kb + 8192;

        // ---- QK^T (swapped): s[kb] = S^T[32kb+key][q], C-init = mask addend ----
        const float* mf = Mf + kt;
        f32x16 s0, s1;
#pragma unroll
        for (int g = 0; g < 4; ++g) {
            float4 m0 = *(const float4*)(mf + 8 * g + 4 * hi);        // kb=0
            float4 m1 = *(const float4*)(mf + 32 + 8 * g + 4 * hi);   // kb=1
            s0[4*g+0] = m0.x; s0[4*g+1] = m0.y; s0[4*g+2] = m0.z; s0[4*g+3] = m0.w;
            s1[4*g+0] = m1.x; s1[4*g+1] = m1.y; s1[4*g+2] = m1.z; s1[4*g+3] = m1.w;
        }
        __builtin_amdgcn_s_setprio(1);
#pragma unroll
        for (int dc = 0; dc < 4; ++dc) {
            bf16x8 k0 = *(const bf16x8*)(Kb + koff(dc,     lane));
            bf16x8 k1 = *(const bf16x8*)(Kb + koff(4 + dc, lane));
            s0 = __builtin_amdgcn_mfma_f32_32x32x16_bf16(k0, qf[dc], s0, 0, 0, 0);
            s1 = __builtin_amdgcn_mfma_f32_32x32x16_bf16(k1, qf[dc], s1, 0, 0, 0);
        }
        __builtin_amdgcn_s_setprio(0);

        // ---- max reduce: 16 pairwise fmax + max3 tree + cross-half ----
        float t[16];
#pragma unroll
        for (int i = 0; i < 16; ++i) t[i] = fmaxf(s0[i], s1[i]);
        float a0 = max3f(t[0],  t[1],  t[2]);
        float a1 = max3f(t[3],  t[4],  t[5]);
        float a2 = max3f(t[6],  t[7],  t[8]);
        float a3 = max3f(t[9],  t[10], t[11]);
        float a4 = max3f(t[12], t[13], t[14]);
        float b0 = max3f(a0, a1, a2);
        float b1 = max3f(a3, a4, t[15]);
        float pmax = xmax(fmaxf(b0, b1));

        float mn = m;
        if (!__all(pmax <= m + THRL)) {       // T13 defer-rescale
            mn = fmaxf(m, pmax);
            float al = __builtin_amdgcn_exp2f(m - mn);
            l *= al;
#pragma unroll
            for (int dt = 0; dt < 2; ++dt)
#pragma unroll
              for (int i = 0; i < 16; ++i) o[dt][i] *= al;
            m = mn;
        }

        // P in-place over S
#pragma unroll
        for (int i = 0; i < 16; ++i) {
            s0[i] = __builtin_amdgcn_exp2f(s0[i] - mn);
            s1[i] = __builtin_amdgcn_exp2f(s1[i] - mn);
        }
        float u[16];
#pragma unroll
        for (int i = 0; i < 16; ++i) u[i] = s0[i] + s1[i];
#pragma unroll
        for (int stp = 8; stp >= 1; stp >>= 1)
#pragma unroll
            for (int i = 0; i < stp; ++i) u[i] += u[i + stp];
        l += xsum(u[0]);

        // ---- pack P -> bf16 pairs (keys (8g+4hi)..+3 per group g) ----
        unsigned pk[2][4][2];
#pragma unroll
        for (int g = 0; g < 4; ++g) {
            pk[0][g][0] = (unsigned)cvt_pk(s0[4*g+0], s0[4*g+1]);
            pk[0][g][1] = (unsigned)cvt_pk(s0[4*g+2], s0[4*g+3]);
            pk[1][g][0] = (unsigned)cvt_pk(s1[4*g+0], s1[4*g+1]);
            pk[1][g][1] = (unsigned)cvt_pk(s1[4*g+2], s1[4*g+3]);
        }

        // ---- PV: O^T += V^T . P^T (P exchanged via permlane32_swap) ----
        __builtin_amdgcn_s_setprio(1);
#pragma unroll
        for (int kc = 0; kc < 4; ++kc) {
            const int kb = kc >> 1, kp = kc & 1;
            union { unsigned u[4]; bf16x8 b; } pu;
            unsigned lo0, hi0, lo1, hi1;
            plswap2(pk[kb][2*kp][0], pk[kb][2*kp+1][0], lo0, hi0, hi);
            plswap2(pk[kb][2*kp][1], pk[kb][2*kp+1][1], lo1, hi1, hi);
            pu.u[0] = lo0; pu.u[1] = lo1; pu.u[2] = hi0; pu.u[3] = hi1;
#pragma unroll
            for (int dt = 0; dt < 2; ++dt) {
                bf16x8 vf = *(const bf16x8*)(Vb + koff(kc * 2 + dt, lane));
                o[dt] = __builtin_amdgcn_mfma_f32_32x32x16_bf16(vf, pu.b, o[dt], 0, 0, 0);
            }
        }
        __builtin_amdgcn_s_setprio(0);

        if (more) {                        // write next tile into other buffer
            char* Kn = smem + (boff ^ 16384);
            WRITEKV(Kn, Kn + 8192)
        }

        __syncthreads();          // cur reads done + next buffer visible
        boff ^= 16384;
    }

    // ---- epilogue: O^T col q=l31, row d = (reg&3)+8*(reg>>2)+4*hi+32*dt ----
    const float invl = 1.0f / l;
    float* op = out + (size_t)h * SQ * DD + (size_t)qrow * DD;
#pragma unroll
    for (int dt = 0; dt < 2; ++dt)
#pragma unroll
      for (int g = 0; g < 4; ++g) {
        float4 r = { o[dt][4*g+0] * invl, o[dt][4*g+1] * invl,
                     o[dt][4*g+2] * invl, o[dt][4*g+3] * invl };
        *(float4*)(op + 32 * dt + 8 * g + 4 * hi) = r;
      }
}

extern "C" void kernel_launch(void* const* d_in, const int* in_sizes, int n_in,
                              void* d_out, int out_size, void* d_ws, size_t ws_size,
                              hipStream_t stream) {
    const float* q = (const float*)d_in[0];
    const float* k = (const float*)d_in[1];
    const float* v = (const float*)d_in[2];
    const int* masks = (const int*)d_in[3];
    float* out = (float*)d_out;
    attn_fwd<<<dim3(512), dim3(256), 0, stream>>>(q, k, v, masks, out);
}